// Round 1
// baseline (936.012 us; speedup 1.0000x reference)
//
#include <hip/hip_runtime.h>

#define NODES   304
#define BATCH   128
#define TSTEPS  20
#define HID     64
#define GCNIN   20
#define NN      (BATCH*NODES)      // 38912
#define NE      (NN*16)            // 622592
#define FC1_IN  (21*NODES)         // 6384
#define FC1_OUT 2048
#define FC2_OUT 300
#define BN_EPS  1e-5f

// ---------------- CSR build ----------------
__global__ void k_count(const int* __restrict__ ei, int* __restrict__ cnt) {
    int e = blockIdx.x * blockDim.x + threadIdx.x;
    if (e < NE) atomicAdd(&cnt[ei[NE + e]], 1);
}

__global__ void k_scan(const int* __restrict__ cnt, int* __restrict__ rowptr,
                       int* __restrict__ cursor) {
    __shared__ int part[1024];
    int tid = threadIdx.x;
    const int CH = NN / 1024;  // 38 exactly
    int base = tid * CH;
    int s = 0;
    for (int i = 0; i < CH; i++) s += cnt[base + i];
    part[tid] = s;
    __syncthreads();
    for (int d = 1; d < 1024; d <<= 1) {
        int v = (tid >= d) ? part[tid - d] : 0;
        __syncthreads();
        part[tid] += v;
        __syncthreads();
    }
    int run = (tid == 0) ? 0 : part[tid - 1];
    for (int i = 0; i < CH; i++) {
        rowptr[base + i] = run;
        cursor[base + i] = run;
        run += cnt[base + i];
    }
    if (tid == 1023) rowptr[NN] = run;
}

__global__ void k_fill(const int* __restrict__ ei, const float* __restrict__ ew,
                       int* __restrict__ cursor, int* __restrict__ row_s,
                       float* __restrict__ w_s) {
    int e = blockIdx.x * blockDim.x + threadIdx.x;
    if (e < NE) {
        int c = ei[NE + e];
        int slot = atomicAdd(&cursor[c], 1);
        row_s[slot] = ei[e];
        w_s[slot] = ew[e];
    }
}

__global__ void k_dinv(const int* __restrict__ rowptr, const float* __restrict__ w_s,
                       float* __restrict__ dinv) {
    int c = blockIdx.x * blockDim.x + threadIdx.x;
    if (c < NN) {
        float s = 1.0f;  // self loop weight
        int j1 = rowptr[c + 1];
        for (int j = rowptr[c]; j < j1; j++) s += w_s[j];
        dinv[c] = rsqrtf(fmaxf(s, 1e-12f));
    }
}

// in-place: w_s[j] -> norm_s[j]
__global__ void k_norm(const int* __restrict__ rowptr, const int* __restrict__ row_s,
                       const float* __restrict__ dinv, float* __restrict__ w_s) {
    int c = blockIdx.x * blockDim.x + threadIdx.x;
    if (c < NN) {
        float dc = dinv[c];
        int j1 = rowptr[c + 1];
        for (int j = rowptr[c]; j < j1; j++)
            w_s[j] = dinv[row_s[j]] * w_s[j] * dc;
    }
}

// ---------------- dense h = X @ W  (one wave per node) ----------------
template <int K>
__global__ __launch_bounds__(64) void k_mmrow(const float* __restrict__ X,
                                              const float* __restrict__ W,
                                              float* __restrict__ H) {
    int n = blockIdx.x;
    int f = threadIdx.x;
    __shared__ float xs[K];
    if (f < K) xs[f] = X[(size_t)n * K + f];
    __syncthreads();
    float acc = 0.f;
#pragma unroll
    for (int k = 0; k < K; k++) acc += xs[k] * W[k * HID + f];
    H[(size_t)n * HID + f] = acc;
}

// ---------------- gather + bias + BN + ReLU ----------------
__global__ __launch_bounds__(64) void k_gather(const int* __restrict__ rowptr,
                                               const int* __restrict__ row_s,
                                               const float* __restrict__ norm_s,
                                               const float* __restrict__ dinv,
                                               const float* __restrict__ H,
                                               const float* __restrict__ gb,
                                               const float* __restrict__ bng,
                                               const float* __restrict__ bnb,
                                               float* __restrict__ XO) {
    int c = blockIdx.x;
    int f = threadIdx.x;
    float dc = dinv[c];
    float acc = H[(size_t)c * HID + f] * dc * dc;  // self loop
    int j1 = rowptr[c + 1];
    for (int j = rowptr[c]; j < j1; j++)
        acc += H[(size_t)row_s[j] * HID + f] * norm_s[j];
    float y = acc + gb[f];
    float scale = bng[f] * rsqrtf(1.f + BN_EPS);
    XO[(size_t)c * HID + f] = fmaxf(y * scale + bnb[f], 0.f);
}

// ---------------- fused temporal conv1 + concat + temporal conv2 + BN2d ----------------
__global__ __launch_bounds__(64) void k_temporal(
    const float* __restrict__ data_x, const float* __restrict__ x2,
    const float* __restrict__ w1, const float* __restrict__ b1,
    const float* __restrict__ w2, const float* __restrict__ b2,
    const float* __restrict__ w3, const float* __restrict__ b3,
    const float* __restrict__ v1, const float* __restrict__ vb1,
    const float* __restrict__ v2, const float* __restrict__ vb2,
    const float* __restrict__ v3, const float* __restrict__ vb3,
    const float* __restrict__ bn2g, const float* __restrict__ bn2b,
    float* __restrict__ tflat) {
    int bn = blockIdx.x;
    int b = bn / NODES, node = bn % NODES;
    int c = threadIdx.x;  // 0..63

    __shared__ float xt[22];          // xt[j] = X[b, j-1, node], zero-padded ends
    __shared__ float trow[23][HID];   // row r = channel r-1 of concat tensor; rows 0,22 = pad

    if (c < TSTEPS) xt[c + 1] = data_x[b * (TSTEPS * NODES) + c * NODES + node];
    if (c == 20) xt[0] = 0.f;
    if (c == 21) xt[21] = 0.f;

    // stage-1 weights: tc1_* shape (64,1,1,3) -> [c*3+k]
    float a10 = w1[c * 3], a11 = w1[c * 3 + 1], a12 = w1[c * 3 + 2], ab1 = b1[c];
    float a20 = w2[c * 3], a21 = w2[c * 3 + 1], a22 = w2[c * 3 + 2], ab2 = b2[c];
    float a30 = w3[c * 3], a31 = w3[c * 3 + 1], a32 = w3[c * 3 + 2], ab3 = b3[c];

    trow[0][c] = 0.f;
    trow[22][c] = 0.f;
    // gfeat channel (20): x.T.reshape scramble resolves to
    //   gfeat[b,node,c] = x2[(b&1)*19456 + node*64 + c][b>>1]
    {
        int n2 = (b & 1) * (NODES * HID) + node * HID + c;
        trow[21][c] = fmaxf(x2[(size_t)n2 * HID + (b >> 1)], 0.f);
    }
    __syncthreads();

#pragma unroll
    for (int t = 0; t < TSTEPS; t++) {
        float x0 = xt[t], xm = xt[t + 1], x2v = xt[t + 2];
        float p = a10 * x0 + a11 * xm + a12 * x2v + ab1;
        float q = a20 * x0 + a21 * xm + a22 * x2v + ab2;
        float r = a30 * x0 + a31 * xm + a32 * x2v + ab3;
        float sg = 1.f / (1.f + __expf(-q));
        trow[t + 1][c] = fmaxf(p * sg + r, 0.f);
    }
    __syncthreads();

    // stage-2 weights: tc2_* shape (1,64,1,3) -> [c*3+k]  (c = input channel)
    float u10 = v1[c * 3], u11 = v1[c * 3 + 1], u12 = v1[c * 3 + 2];
    float u20 = v2[c * 3], u21 = v2[c * 3 + 1], u22 = v2[c * 3 + 2];
    float u30 = v3[c * 3], u31 = v3[c * 3 + 1], u32 = v3[c * 3 + 2];
    float s2 = bn2g[node] * rsqrtf(1.f + BN_EPS);
    float bb2 = bn2b[node];
    float B1 = vb1[0], B2 = vb2[0], B3 = vb3[0];

    for (int t2 = 0; t2 < 21; t2++) {
        float r0 = trow[t2][c], r1 = trow[t2 + 1][c], r2 = trow[t2 + 2][c];
        float pp = u10 * r0 + u11 * r1 + u12 * r2;
        float qq = u20 * r0 + u21 * r1 + u22 * r2;
        float rr = u30 * r0 + u31 * r1 + u32 * r2;
#pragma unroll
        for (int m = 32; m; m >>= 1) {
            pp += __shfl_xor(pp, m);
            qq += __shfl_xor(qq, m);
            rr += __shfl_xor(rr, m);
        }
        if (c == 0) {
            float P = pp + B1, Q = qq + B2, R = rr + B3;
            float sg = 1.f / (1.f + __expf(-Q));
            float hv = fmaxf(P * sg + R, 0.f);
            tflat[(size_t)b * FC1_IN + t2 * NODES + node] = hv * s2 + bb2;
        }
    }
}

// ---------------- FC layers ----------------
__global__ __launch_bounds__(256) void k_fc1(const float* __restrict__ A,
                                             const float* __restrict__ W,
                                             const float* __restrict__ bias,
                                             float* __restrict__ O) {
    int olane = threadIdx.x & 63;
    int brow = threadIdx.x >> 6;
    int o = blockIdx.x * 64 + olane;
    int b = blockIdx.y * 4 + brow;
    const float* a = A + (size_t)b * FC1_IN;
    float acc = 0.f;
    for (int k = 0; k < FC1_IN; k++) acc += a[k] * W[(size_t)k * FC1_OUT + o];
    O[(size_t)b * FC1_OUT + o] = fmaxf(acc + bias[o], 0.f);
}

__global__ __launch_bounds__(64) void k_fc2(const float* __restrict__ A,
                                            const float* __restrict__ W,
                                            const float* __restrict__ bias,
                                            float* __restrict__ O) {
    int o = blockIdx.x * 64 + threadIdx.x;
    int b = blockIdx.y;
    if (o >= FC2_OUT) return;
    const float* a = A + (size_t)b * FC1_OUT;
    float acc = 0.f;
    for (int k = 0; k < FC1_OUT; k++) acc += a[k] * W[(size_t)k * FC2_OUT + o];
    O[(size_t)b * FC2_OUT + o] = acc + bias[o];
}

extern "C" void kernel_launch(void* const* d_in, const int* in_sizes, int n_in,
                              void* d_out, int out_size, void* d_ws, size_t ws_size,
                              hipStream_t stream) {
    const float* data_x = (const float*)d_in[0];
    const int* ei = (const int*)d_in[1];
    const float* ew = (const float*)d_in[2];
    const float* tc1w1 = (const float*)d_in[3];
    const float* tc1b1 = (const float*)d_in[4];
    const float* tc1w2 = (const float*)d_in[5];
    const float* tc1b2 = (const float*)d_in[6];
    const float* tc1w3 = (const float*)d_in[7];
    const float* tc1b3 = (const float*)d_in[8];
    const float* W0 = (const float*)d_in[9];
    const float* gb0 = (const float*)d_in[10];
    const float* bn0g = (const float*)d_in[11];
    const float* bn0b = (const float*)d_in[12];
    const float* W1 = (const float*)d_in[13];
    const float* gb1 = (const float*)d_in[14];
    const float* bn1g = (const float*)d_in[15];
    const float* bn1b = (const float*)d_in[16];
    const float* tc2w1 = (const float*)d_in[17];
    const float* tc2b1 = (const float*)d_in[18];
    const float* tc2w2 = (const float*)d_in[19];
    const float* tc2b2 = (const float*)d_in[20];
    const float* tc2w3 = (const float*)d_in[21];
    const float* tc2b3 = (const float*)d_in[22];
    const float* bn2g = (const float*)d_in[23];
    const float* bn2b = (const float*)d_in[24];
    const float* fcW = (const float*)d_in[25];
    const float* fcb = (const float*)d_in[26];
    const float* fc4W = (const float*)d_in[27];
    const float* fc4b = (const float*)d_in[28];
    float* out = (float*)d_out;

    char* ws = (char*)d_ws;
    size_t off = 0;
    auto alloc = [&](size_t bytes) -> void* {
        void* p = ws + off;
        off = (off + bytes + 255) & ~(size_t)255;
        return p;
    };
    int* cnt = (int*)alloc((size_t)NN * 4);
    int* rowptr = (int*)alloc((size_t)(NN + 1) * 4);
    int* cursor = (int*)alloc((size_t)NN * 4);
    int* row_s = (int*)alloc((size_t)NE * 4);
    float* w_s = (float*)alloc((size_t)NE * 4);  // becomes norm_s in place
    float* dinv = (float*)alloc((size_t)NN * 4);
    float* h = (float*)alloc((size_t)NN * HID * 4);
    float* x1 = (float*)alloc((size_t)NN * HID * 4);
    float* x2 = (float*)alloc((size_t)NN * HID * 4);
    float* tflat = (float*)alloc((size_t)BATCH * FC1_IN * 4);
    float* fc1o = (float*)alloc((size_t)BATCH * FC1_OUT * 4);
    (void)ws_size;
    (void)in_sizes;
    (void)n_in;
    (void)out_size;

    hipMemsetAsync(cnt, 0, (size_t)NN * 4, stream);
    k_count<<<(NE + 255) / 256, 256, 0, stream>>>(ei, cnt);
    k_scan<<<1, 1024, 0, stream>>>(cnt, rowptr, cursor);
    k_fill<<<(NE + 255) / 256, 256, 0, stream>>>(ei, ew, cursor, row_s, w_s);
    k_dinv<<<(NN + 255) / 256, 256, 0, stream>>>(rowptr, w_s, dinv);
    k_norm<<<(NN + 255) / 256, 256, 0, stream>>>(rowptr, row_s, dinv, w_s);

    k_mmrow<GCNIN><<<NN, 64, 0, stream>>>(data_x, W0, h);
    k_gather<<<NN, 64, 0, stream>>>(rowptr, row_s, w_s, dinv, h, gb0, bn0g, bn0b, x1);
    k_mmrow<HID><<<NN, 64, 0, stream>>>(x1, W1, h);
    k_gather<<<NN, 64, 0, stream>>>(rowptr, row_s, w_s, dinv, h, gb1, bn1g, bn1b, x2);

    k_temporal<<<NN, 64, 0, stream>>>(data_x, x2, tc1w1, tc1b1, tc1w2, tc1b2, tc1w3,
                                      tc1b3, tc2w1, tc2b1, tc2w2, tc2b2, tc2w3, tc2b3,
                                      bn2g, bn2b, tflat);

    dim3 g1(FC1_OUT / 64, BATCH / 4);
    k_fc1<<<g1, 256, 0, stream>>>(tflat, fcW, fcb, fc1o);
    dim3 g2((FC2_OUT + 63) / 64, BATCH);
    k_fc2<<<g2, 64, 0, stream>>>(fc1o, fc4W, fc4b, out);
}

// Round 2
// 473.760 us; speedup vs baseline: 1.9757x; 1.9757x over previous
//
#include <hip/hip_runtime.h>

#define NODES   304
#define BATCH   128
#define TSTEPS  20
#define HID     64
#define GCNIN   20
#define NN      (BATCH*NODES)      // 38912
#define NE      (NN*16)            // 622592
#define FC1_IN  (21*NODES)         // 6384
#define KP1     6400               // FC1_IN padded to /32
#define FC1_OUT 2048
#define FC2_OUT 300
#define NP2     304                // FC2_OUT padded to /16
#define BN_EPS  1e-5f

typedef __attribute__((ext_vector_type(8))) short short8;
typedef __attribute__((ext_vector_type(4))) float f32x4;

static __device__ __forceinline__ short f2bf(float x) {
    unsigned u = __float_as_uint(x);
    unsigned r = (u + 0x7FFF + ((u >> 16) & 1)) >> 16;  // RNE
    return (short)r;
}

// ---------------- CSR build ----------------
__global__ void k_count(const int* __restrict__ ei, int* __restrict__ cnt) {
    int e = blockIdx.x * blockDim.x + threadIdx.x;
    if (e < NE) atomicAdd(&cnt[ei[NE + e]], 1);
}

__global__ void k_scan(const int* __restrict__ cnt, int* __restrict__ rowptr,
                       int* __restrict__ cursor) {
    __shared__ int part[1024];
    int tid = threadIdx.x;
    const int CH = NN / 1024;  // 38 exactly
    int base = tid * CH;
    int s = 0;
    for (int i = 0; i < CH; i++) s += cnt[base + i];
    part[tid] = s;
    __syncthreads();
    for (int d = 1; d < 1024; d <<= 1) {
        int v = (tid >= d) ? part[tid - d] : 0;
        __syncthreads();
        part[tid] += v;
        __syncthreads();
    }
    int run = (tid == 0) ? 0 : part[tid - 1];
    for (int i = 0; i < CH; i++) {
        rowptr[base + i] = run;
        cursor[base + i] = run;
        run += cnt[base + i];
    }
    if (tid == 1023) rowptr[NN] = run;
}

__global__ void k_fill(const int* __restrict__ ei, const float* __restrict__ ew,
                       int* __restrict__ cursor, int* __restrict__ row_s,
                       float* __restrict__ w_s) {
    int e = blockIdx.x * blockDim.x + threadIdx.x;
    if (e < NE) {
        int c = ei[NE + e];
        int slot = atomicAdd(&cursor[c], 1);
        row_s[slot] = ei[e];
        w_s[slot] = ew[e];
    }
}

__global__ void k_dinv(const int* __restrict__ rowptr, const float* __restrict__ w_s,
                       float* __restrict__ dinv) {
    int c = blockIdx.x * blockDim.x + threadIdx.x;
    if (c < NN) {
        float s = 1.0f;  // self loop weight
        int j1 = rowptr[c + 1];
        for (int j = rowptr[c]; j < j1; j++) s += w_s[j];
        dinv[c] = rsqrtf(fmaxf(s, 1e-12f));
    }
}

// in-place: w_s[j] -> norm_s[j]
__global__ void k_norm(const int* __restrict__ rowptr, const int* __restrict__ row_s,
                       const float* __restrict__ dinv, float* __restrict__ w_s) {
    int c = blockIdx.x * blockDim.x + threadIdx.x;
    if (c < NN) {
        float dc = dinv[c];
        int j1 = rowptr[c + 1];
        for (int j = rowptr[c]; j < j1; j++)
            w_s[j] = dinv[row_s[j]] * w_s[j] * dc;
    }
}

// ---------------- dense h = X @ W  (one wave per node) ----------------
template <int K>
__global__ __launch_bounds__(64) void k_mmrow(const float* __restrict__ X,
                                              const float* __restrict__ W,
                                              float* __restrict__ H) {
    int n = blockIdx.x;
    int f = threadIdx.x;
    __shared__ float xs[K];
    if (f < K) xs[f] = X[(size_t)n * K + f];
    __syncthreads();
    float acc = 0.f;
#pragma unroll
    for (int k = 0; k < K; k++) acc += xs[k] * W[k * HID + f];
    H[(size_t)n * HID + f] = acc;
}

// ---------------- gather + bias + BN + ReLU ----------------
__global__ __launch_bounds__(64) void k_gather(const int* __restrict__ rowptr,
                                               const int* __restrict__ row_s,
                                               const float* __restrict__ norm_s,
                                               const float* __restrict__ dinv,
                                               const float* __restrict__ H,
                                               const float* __restrict__ gb,
                                               const float* __restrict__ bng,
                                               const float* __restrict__ bnb,
                                               float* __restrict__ XO) {
    int c = blockIdx.x;
    int f = threadIdx.x;
    float dc = dinv[c];
    float acc = H[(size_t)c * HID + f] * dc * dc;  // self loop
    int j1 = rowptr[c + 1];
    for (int j = rowptr[c]; j < j1; j++)
        acc += H[(size_t)row_s[j] * HID + f] * norm_s[j];
    float y = acc + gb[f];
    float scale = bng[f] * rsqrtf(1.f + BN_EPS);
    XO[(size_t)c * HID + f] = fmaxf(y * scale + bnb[f], 0.f);
}

// ---------------- fused temporal conv1 + concat + temporal conv2 + BN2d ----------------
__global__ __launch_bounds__(64) void k_temporal(
    const float* __restrict__ data_x, const float* __restrict__ x2,
    const float* __restrict__ w1, const float* __restrict__ b1,
    const float* __restrict__ w2, const float* __restrict__ b2,
    const float* __restrict__ w3, const float* __restrict__ b3,
    const float* __restrict__ v1, const float* __restrict__ vb1,
    const float* __restrict__ v2, const float* __restrict__ vb2,
    const float* __restrict__ v3, const float* __restrict__ vb3,
    const float* __restrict__ bn2g, const float* __restrict__ bn2b,
    float* __restrict__ tflat) {
    int bn = blockIdx.x;
    int b = bn / NODES, node = bn % NODES;
    int c = threadIdx.x;  // 0..63

    __shared__ float xt[22];          // xt[j] = X[b, j-1, node], zero-padded ends
    __shared__ float trow[23][HID];   // row r = channel r-1 of concat tensor; rows 0,22 = pad

    if (c < TSTEPS) xt[c + 1] = data_x[b * (TSTEPS * NODES) + c * NODES + node];
    if (c == 20) xt[0] = 0.f;
    if (c == 21) xt[21] = 0.f;

    float a10 = w1[c * 3], a11 = w1[c * 3 + 1], a12 = w1[c * 3 + 2], ab1 = b1[c];
    float a20 = w2[c * 3], a21 = w2[c * 3 + 1], a22 = w2[c * 3 + 2], ab2 = b2[c];
    float a30 = w3[c * 3], a31 = w3[c * 3 + 1], a32 = w3[c * 3 + 2], ab3 = b3[c];

    trow[0][c] = 0.f;
    trow[22][c] = 0.f;
    // gfeat[b,node,c] = x2[(b&1)*19456 + node*64 + c][b>>1]
    {
        int n2 = (b & 1) * (NODES * HID) + node * HID + c;
        trow[21][c] = fmaxf(x2[(size_t)n2 * HID + (b >> 1)], 0.f);
    }
    __syncthreads();

#pragma unroll
    for (int t = 0; t < TSTEPS; t++) {
        float x0 = xt[t], xm = xt[t + 1], x2v = xt[t + 2];
        float p = a10 * x0 + a11 * xm + a12 * x2v + ab1;
        float q = a20 * x0 + a21 * xm + a22 * x2v + ab2;
        float r = a30 * x0 + a31 * xm + a32 * x2v + ab3;
        float sg = 1.f / (1.f + __expf(-q));
        trow[t + 1][c] = fmaxf(p * sg + r, 0.f);
    }
    __syncthreads();

    float u10 = v1[c * 3], u11 = v1[c * 3 + 1], u12 = v1[c * 3 + 2];
    float u20 = v2[c * 3], u21 = v2[c * 3 + 1], u22 = v2[c * 3 + 2];
    float u30 = v3[c * 3], u31 = v3[c * 3 + 1], u32 = v3[c * 3 + 2];
    float s2 = bn2g[node] * rsqrtf(1.f + BN_EPS);
    float bb2 = bn2b[node];
    float B1 = vb1[0], B2 = vb2[0], B3 = vb3[0];

    for (int t2 = 0; t2 < 21; t2++) {
        float r0 = trow[t2][c], r1 = trow[t2 + 1][c], r2 = trow[t2 + 2][c];
        float pp = u10 * r0 + u11 * r1 + u12 * r2;
        float qq = u20 * r0 + u21 * r1 + u22 * r2;
        float rr = u30 * r0 + u31 * r1 + u32 * r2;
#pragma unroll
        for (int m = 32; m; m >>= 1) {
            pp += __shfl_xor(pp, m);
            qq += __shfl_xor(qq, m);
            rr += __shfl_xor(rr, m);
        }
        if (c == 0) {
            float P = pp + B1, Q = qq + B2, R = rr + B3;
            float sg = 1.f / (1.f + __expf(-Q));
            float hv = fmaxf(P * sg + R, 0.f);
            tflat[(size_t)b * FC1_IN + t2 * NODES + node] = hv * s2 + bb2;
        }
    }
}

// ---------------- bf16 converts ----------------
__global__ __launch_bounds__(256) void k_cvtA(const float* __restrict__ src,
                                              short* __restrict__ dst) {
    int idx = blockIdx.x * 256 + threadIdx.x;  // over BATCH*KP1
    if (idx >= BATCH * KP1) return;
    int b = idx / KP1, k = idx % KP1;
    dst[idx] = (k < FC1_IN) ? f2bf(src[(size_t)b * FC1_IN + k]) : (short)0;
}

// fcW [6384][2048] f32 -> Wt [2048][6400] bf16 (transposed, K-padded)
__global__ __launch_bounds__(256) void k_cvtW(const float* __restrict__ W,
                                              short* __restrict__ Wt) {
    __shared__ float t[32][33];
    int tx = threadIdx.x & 31, ty = threadIdx.x >> 5;  // 32 x 8
    int n0 = blockIdx.x * 32, k0 = blockIdx.y * 32;
#pragma unroll
    for (int r = 0; r < 32; r += 8) {
        int k = k0 + r + ty;
        t[r + ty][tx] = (k < FC1_IN) ? W[(size_t)k * FC1_OUT + n0 + tx] : 0.f;
    }
    __syncthreads();
#pragma unroll
    for (int r = 0; r < 32; r += 8) {
        int n = n0 + r + ty;
        Wt[(size_t)n * KP1 + k0 + tx] = f2bf(t[tx][r + ty]);
    }
}

// fc4W [2048][300] f32 -> W4t [304][2048] bf16 (transposed, N-padded)
__global__ __launch_bounds__(256) void k_cvtW4(const float* __restrict__ W,
                                               short* __restrict__ Wt) {
    __shared__ float t[32][33];
    int tx = threadIdx.x & 31, ty = threadIdx.x >> 5;
    int n0 = blockIdx.x * 32, k0 = blockIdx.y * 32;
#pragma unroll
    for (int r = 0; r < 32; r += 8) {
        int k = k0 + r + ty, n = n0 + tx;
        t[r + ty][tx] = (n < FC2_OUT) ? W[(size_t)k * FC2_OUT + n] : 0.f;
    }
    __syncthreads();
#pragma unroll
    for (int r = 0; r < 32; r += 8) {
        int n = n0 + r + ty;
        if (n < NP2) Wt[(size_t)n * FC1_OUT + k0 + tx] = f2bf(t[tx][r + ty]);
    }
}

// ---------------- FC1 MFMA GEMM: [128 x 6400] @ [6400 x 2048], split-K ----------------
#define KSPL1 8
#define KCH1  (KP1 / KSPL1)  // 800
__global__ __launch_bounds__(256) void k_gemm1(const short* __restrict__ Ab,
                                               const short* __restrict__ Wt,
                                               float* __restrict__ part) {
    int lane = threadIdx.x & 63, wv = threadIdx.x >> 6;
    int r = lane & 15, kg = lane >> 4;
    int nb = blockIdx.x * 64, sp = blockIdx.y;

    f32x4 acc[2][4] = {};
    const short* a0 = Ab + (size_t)(wv * 32 + r) * KP1;
    const short* a1 = a0 + (size_t)16 * KP1;
    const short* bp0 = Wt + (size_t)(nb + r) * KP1;
    const short* bp1 = bp0 + (size_t)16 * KP1;
    const short* bp2 = bp0 + (size_t)32 * KP1;
    const short* bp3 = bp0 + (size_t)48 * KP1;

    int k0 = sp * KCH1 + kg * 8;
#pragma unroll 1
    for (int s = 0; s < KCH1 / 32; s++, k0 += 32) {
        short8 av0 = *(const short8*)(a0 + k0);
        short8 av1 = *(const short8*)(a1 + k0);
        short8 bv0 = *(const short8*)(bp0 + k0);
        short8 bv1 = *(const short8*)(bp1 + k0);
        short8 bv2 = *(const short8*)(bp2 + k0);
        short8 bv3 = *(const short8*)(bp3 + k0);
        acc[0][0] = __builtin_amdgcn_mfma_f32_16x16x32_bf16(av0, bv0, acc[0][0], 0, 0, 0);
        acc[1][0] = __builtin_amdgcn_mfma_f32_16x16x32_bf16(av1, bv0, acc[1][0], 0, 0, 0);
        acc[0][1] = __builtin_amdgcn_mfma_f32_16x16x32_bf16(av0, bv1, acc[0][1], 0, 0, 0);
        acc[1][1] = __builtin_amdgcn_mfma_f32_16x16x32_bf16(av1, bv1, acc[1][1], 0, 0, 0);
        acc[0][2] = __builtin_amdgcn_mfma_f32_16x16x32_bf16(av0, bv2, acc[0][2], 0, 0, 0);
        acc[1][2] = __builtin_amdgcn_mfma_f32_16x16x32_bf16(av1, bv2, acc[1][2], 0, 0, 0);
        acc[0][3] = __builtin_amdgcn_mfma_f32_16x16x32_bf16(av0, bv3, acc[0][3], 0, 0, 0);
        acc[1][3] = __builtin_amdgcn_mfma_f32_16x16x32_bf16(av1, bv3, acc[1][3], 0, 0, 0);
    }

    float* dst = part + (size_t)sp * BATCH * FC1_OUT;
#pragma unroll
    for (int m = 0; m < 2; m++)
#pragma unroll
        for (int f = 0; f < 4; f++)
#pragma unroll
            for (int j = 0; j < 4; j++) {
                int row = wv * 32 + m * 16 + kg * 4 + j;
                int col = nb + f * 16 + r;
                dst[(size_t)row * FC1_OUT + col] = acc[m][f][j];
            }
}

// reduce split-K + bias + ReLU -> bf16 activations for FC2
__global__ __launch_bounds__(256) void k_reduce1(const float* __restrict__ part,
                                                 const float* __restrict__ bias,
                                                 short* __restrict__ Ab2) {
    int idx = blockIdx.x * 256 + threadIdx.x;  // b*2048+o
    int o = idx & (FC1_OUT - 1);
    float s = bias[o];
#pragma unroll
    for (int sp = 0; sp < KSPL1; sp++) s += part[(size_t)sp * BATCH * FC1_OUT + idx];
    Ab2[idx] = f2bf(fmaxf(s, 0.f));
}

// ---------------- FC2 MFMA GEMM: [128 x 2048] @ [2048 x 304], split-K ----------------
#define KSPL2 8
#define KCH2  (FC1_OUT / KSPL2)  // 256
__global__ __launch_bounds__(256) void k_gemm2(const short* __restrict__ Ab,
                                               const short* __restrict__ Wt,
                                               float* __restrict__ part) {
    int lane = threadIdx.x & 63, wv = threadIdx.x >> 6;
    int r = lane & 15, kg = lane >> 4;
    int nb = blockIdx.x * 16, sp = blockIdx.y;

    f32x4 acc[2] = {};
    const short* a0 = Ab + (size_t)(wv * 32 + r) * FC1_OUT;
    const short* a1 = a0 + (size_t)16 * FC1_OUT;
    const short* bp = Wt + (size_t)(nb + r) * FC1_OUT;

    int k0 = sp * KCH2 + kg * 8;
#pragma unroll
    for (int s = 0; s < KCH2 / 32; s++, k0 += 32) {
        short8 av0 = *(const short8*)(a0 + k0);
        short8 av1 = *(const short8*)(a1 + k0);
        short8 bv = *(const short8*)(bp + k0);
        acc[0] = __builtin_amdgcn_mfma_f32_16x16x32_bf16(av0, bv, acc[0], 0, 0, 0);
        acc[1] = __builtin_amdgcn_mfma_f32_16x16x32_bf16(av1, bv, acc[1], 0, 0, 0);
    }

    float* dst = part + (size_t)sp * BATCH * NP2;
#pragma unroll
    for (int m = 0; m < 2; m++)
#pragma unroll
        for (int j = 0; j < 4; j++) {
            int row = wv * 32 + m * 16 + kg * 4 + j;
            int col = nb + r;
            dst[(size_t)row * NP2 + col] = acc[m][j];
        }
}

__global__ __launch_bounds__(256) void k_reduce2(const float* __restrict__ part,
                                                 const float* __restrict__ bias,
                                                 float* __restrict__ out) {
    int idx = blockIdx.x * 256 + threadIdx.x;  // over BATCH*NP2
    if (idx >= BATCH * NP2) return;
    int b = idx / NP2, o = idx % NP2;
    float s = 0.f;
#pragma unroll
    for (int sp = 0; sp < KSPL2; sp++) s += part[(size_t)sp * BATCH * NP2 + idx];
    if (o < FC2_OUT) out[(size_t)b * FC2_OUT + o] = s + bias[o];
}

extern "C" void kernel_launch(void* const* d_in, const int* in_sizes, int n_in,
                              void* d_out, int out_size, void* d_ws, size_t ws_size,
                              hipStream_t stream) {
    const float* data_x = (const float*)d_in[0];
    const int* ei = (const int*)d_in[1];
    const float* ew = (const float*)d_in[2];
    const float* tc1w1 = (const float*)d_in[3];
    const float* tc1b1 = (const float*)d_in[4];
    const float* tc1w2 = (const float*)d_in[5];
    const float* tc1b2 = (const float*)d_in[6];
    const float* tc1w3 = (const float*)d_in[7];
    const float* tc1b3 = (const float*)d_in[8];
    const float* W0 = (const float*)d_in[9];
    const float* gb0 = (const float*)d_in[10];
    const float* bn0g = (const float*)d_in[11];
    const float* bn0b = (const float*)d_in[12];
    const float* W1 = (const float*)d_in[13];
    const float* gb1 = (const float*)d_in[14];
    const float* bn1g = (const float*)d_in[15];
    const float* bn1b = (const float*)d_in[16];
    const float* tc2w1 = (const float*)d_in[17];
    const float* tc2b1 = (const float*)d_in[18];
    const float* tc2w2 = (const float*)d_in[19];
    const float* tc2b2 = (const float*)d_in[20];
    const float* tc2w3 = (const float*)d_in[21];
    const float* tc2b3 = (const float*)d_in[22];
    const float* bn2g = (const float*)d_in[23];
    const float* bn2b = (const float*)d_in[24];
    const float* fcW = (const float*)d_in[25];
    const float* fcb = (const float*)d_in[26];
    const float* fc4W = (const float*)d_in[27];
    const float* fc4b = (const float*)d_in[28];
    float* out = (float*)d_out;

    char* ws = (char*)d_ws;
    // persistent region
    float* x2 = (float*)(ws + 0);                  // 9,961,472 B
    float* tflat = (float*)(ws + 9961472);         // 3,268,608 B
    const size_t ARENA = 9961472 + 3268608;        // 13,230,080

    // arena A (GCN phase)
    size_t off = ARENA;
    auto alloc = [&](size_t bytes) -> void* {
        void* p = ws + off;
        off = (off + bytes + 255) & ~(size_t)255;
        return p;
    };
    int* cnt = (int*)alloc((size_t)NN * 4);
    int* rowptr = (int*)alloc((size_t)(NN + 1) * 4);
    int* cursor = (int*)alloc((size_t)NN * 4);
    int* row_s = (int*)alloc((size_t)NE * 4);
    float* w_s = (float*)alloc((size_t)NE * 4);
    float* dinv = (float*)alloc((size_t)NN * 4);
    float* h = (float*)alloc((size_t)NN * HID * 4);
    float* x1 = (float*)alloc((size_t)NN * HID * 4);

    // arena C (FC phase) — overlaps arena A, used only after temporal
    off = ARENA;
    short* Ab = (short*)alloc((size_t)BATCH * KP1 * 2);
    short* Wt = (short*)alloc((size_t)FC1_OUT * KP1 * 2);
    float* part1 = (float*)alloc((size_t)KSPL1 * BATCH * FC1_OUT * 4);
    short* Ab2 = (short*)alloc((size_t)BATCH * FC1_OUT * 2);
    short* W4t = (short*)alloc((size_t)NP2 * FC1_OUT * 2);
    float* part2 = (float*)alloc((size_t)KSPL2 * BATCH * NP2 * 4);
    (void)ws_size; (void)in_sizes; (void)n_in; (void)out_size;

    // ---- CSR ----
    hipMemsetAsync(cnt, 0, (size_t)NN * 4, stream);
    k_count<<<(NE + 255) / 256, 256, 0, stream>>>(ei, cnt);
    k_scan<<<1, 1024, 0, stream>>>(cnt, rowptr, cursor);
    k_fill<<<(NE + 255) / 256, 256, 0, stream>>>(ei, ew, cursor, row_s, w_s);
    k_dinv<<<(NN + 255) / 256, 256, 0, stream>>>(rowptr, w_s, dinv);
    k_norm<<<(NN + 255) / 256, 256, 0, stream>>>(rowptr, row_s, dinv, w_s);

    // ---- GCN ----
    k_mmrow<GCNIN><<<NN, 64, 0, stream>>>(data_x, W0, h);
    k_gather<<<NN, 64, 0, stream>>>(rowptr, row_s, w_s, dinv, h, gb0, bn0g, bn0b, x1);
    k_mmrow<HID><<<NN, 64, 0, stream>>>(x1, W1, h);
    k_gather<<<NN, 64, 0, stream>>>(rowptr, row_s, w_s, dinv, h, gb1, bn1g, bn1b, x2);

    // ---- temporal ----
    k_temporal<<<NN, 64, 0, stream>>>(data_x, x2, tc1w1, tc1b1, tc1w2, tc1b2, tc1w3,
                                      tc1b3, tc2w1, tc2b1, tc2w2, tc2b2, tc2w3, tc2b3,
                                      bn2g, bn2b, tflat);

    // ---- FC (bf16 MFMA) ----
    k_cvtA<<<(BATCH * KP1 + 255) / 256, 256, 0, stream>>>(tflat, Ab);
    {
        dim3 g(FC1_OUT / 32, KP1 / 32);
        k_cvtW<<<g, 256, 0, stream>>>(fcW, Wt);
    }
    {
        dim3 g(FC1_OUT / 64, KSPL1);
        k_gemm1<<<g, 256, 0, stream>>>(Ab, Wt, part1);
    }
    k_reduce1<<<BATCH * FC1_OUT / 256, 256, 0, stream>>>(part1, fcb, Ab2);
    {
        dim3 g((NP2 + 31) / 32, FC1_OUT / 32);
        k_cvtW4<<<g, 256, 0, stream>>>(fc4W, W4t);
    }
    {
        dim3 g(NP2 / 16, KSPL2);
        k_gemm2<<<g, 256, 0, stream>>>(Ab2, W4t, part2);
    }
    k_reduce2<<<(BATCH * NP2 + 255) / 256, 256, 0, stream>>>(part2, fc4b, out);
}

// Round 3
// 378.946 us; speedup vs baseline: 2.4700x; 1.2502x over previous
//
#include <hip/hip_runtime.h>

#define NODES   304
#define BATCH   128
#define TSTEPS  20
#define HID     64
#define GCNIN   20
#define NN      (BATCH*NODES)      // 38912
#define NE      (NN*16)            // 622592
#define FC1_IN  (21*NODES)         // 6384
#define KP1     6400               // FC1_IN padded to /32
#define FC1_OUT 2048
#define FC2_OUT 300
#define NP2     304                // FC2_OUT padded to /16
#define BN_EPS  1e-5f

typedef __attribute__((ext_vector_type(8))) short short8;
typedef __attribute__((ext_vector_type(4))) float f32x4;

static __device__ __forceinline__ short f2bf(float x) {
    unsigned u = __float_as_uint(x);
    unsigned r = (u + 0x7FFF + ((u >> 16) & 1)) >> 16;  // RNE
    return (short)r;
}

// DPP row_ror add: v += ror<N>(v) within 16-lane row (VALU pipe, no DS ops)
template <int C>
static __device__ __forceinline__ float dppadd(float v) {
    return v + __int_as_float(
        __builtin_amdgcn_update_dpp(0, __float_as_int(v), C, 0xF, 0xF, false));
}
// full sum across the 16-lane row; result in all 16 lanes
static __device__ __forceinline__ float rsum16(float v) {
    v = dppadd<0x128>(v);  // row_ror:8
    v = dppadd<0x124>(v);  // row_ror:4
    v = dppadd<0x122>(v);  // row_ror:2
    v = dppadd<0x121>(v);  // row_ror:1
    return v;
}

// ---------------- CSR build ----------------
__global__ void k_count(const int* __restrict__ ei, int* __restrict__ cnt) {
    int e = blockIdx.x * blockDim.x + threadIdx.x;
    if (e < NE) atomicAdd(&cnt[ei[NE + e]], 1);
}

__global__ void k_scan(const int* __restrict__ cnt, int* __restrict__ rowptr,
                       int* __restrict__ cursor) {
    __shared__ int part[1024];
    int tid = threadIdx.x;
    const int CH = NN / 1024;  // 38 exactly
    int base = tid * CH;
    int s = 0;
    for (int i = 0; i < CH; i++) s += cnt[base + i];
    part[tid] = s;
    __syncthreads();
    for (int d = 1; d < 1024; d <<= 1) {
        int v = (tid >= d) ? part[tid - d] : 0;
        __syncthreads();
        part[tid] += v;
        __syncthreads();
    }
    int run = (tid == 0) ? 0 : part[tid - 1];
    for (int i = 0; i < CH; i++) {
        rowptr[base + i] = run;
        cursor[base + i] = run;
        run += cnt[base + i];
    }
    if (tid == 1023) rowptr[NN] = run;
}

__global__ void k_fill(const int* __restrict__ ei, const float* __restrict__ ew,
                       int* __restrict__ cursor, int* __restrict__ row_s,
                       float* __restrict__ w_s) {
    int e = blockIdx.x * blockDim.x + threadIdx.x;
    if (e < NE) {
        int c = ei[NE + e];
        int slot = atomicAdd(&cursor[c], 1);
        row_s[slot] = ei[e];
        w_s[slot] = ew[e];
    }
}

__global__ void k_dinv(const int* __restrict__ rowptr, const float* __restrict__ w_s,
                       float* __restrict__ dinv) {
    int c = blockIdx.x * blockDim.x + threadIdx.x;
    if (c < NN) {
        float s = 1.0f;  // self loop weight
        int j1 = rowptr[c + 1];
        for (int j = rowptr[c]; j < j1; j++) s += w_s[j];
        dinv[c] = rsqrtf(fmaxf(s, 1e-12f));
    }
}

// in-place: w_s[j] -> norm_s[j]
__global__ void k_norm(const int* __restrict__ rowptr, const int* __restrict__ row_s,
                       const float* __restrict__ dinv, float* __restrict__ w_s) {
    int c = blockIdx.x * blockDim.x + threadIdx.x;
    if (c < NN) {
        float dc = dinv[c];
        int j1 = rowptr[c + 1];
        for (int j = rowptr[c]; j < j1; j++)
            w_s[j] = dinv[row_s[j]] * w_s[j] * dc;
    }
}

// ---------------- dense h = X @ W  (one wave per node) ----------------
template <int K>
__global__ __launch_bounds__(64) void k_mmrow(const float* __restrict__ X,
                                              const float* __restrict__ W,
                                              float* __restrict__ H) {
    int n = blockIdx.x;
    int f = threadIdx.x;
    __shared__ float xs[K];
    if (f < K) xs[f] = X[(size_t)n * K + f];
    __syncthreads();
    float acc = 0.f;
#pragma unroll
    for (int k = 0; k < K; k++) acc += xs[k] * W[k * HID + f];
    H[(size_t)n * HID + f] = acc;
}

// ---------------- gather + bias + BN + ReLU ----------------
__global__ __launch_bounds__(64) void k_gather(const int* __restrict__ rowptr,
                                               const int* __restrict__ row_s,
                                               const float* __restrict__ norm_s,
                                               const float* __restrict__ dinv,
                                               const float* __restrict__ H,
                                               const float* __restrict__ gb,
                                               const float* __restrict__ bng,
                                               const float* __restrict__ bnb,
                                               float* __restrict__ XO) {
    int c = blockIdx.x;
    int f = threadIdx.x;
    float dc = dinv[c];
    float acc = H[(size_t)c * HID + f] * dc * dc;  // self loop
    int j1 = rowptr[c + 1];
    for (int j = rowptr[c]; j < j1; j++)
        acc += H[(size_t)row_s[j] * HID + f] * norm_s[j];
    float y = acc + gb[f];
    float scale = bng[f] * rsqrtf(1.f + BN_EPS);
    XO[(size_t)c * HID + f] = fmaxf(y * scale + bnb[f], 0.f);
}

// ---------------- x2 [38912][64] -> x2t [64][38912] ----------------
__global__ __launch_bounds__(256) void k_xpose(const float* __restrict__ x2,
                                               float* __restrict__ x2t) {
    __shared__ float tile[64][65];
    int n0 = blockIdx.x * 64;
    for (int i = threadIdx.x; i < 4096; i += 256) {
        int r = i >> 6, h = i & 63;
        tile[r][h] = x2[(size_t)(n0 + r) * 64 + h];
    }
    __syncthreads();
    for (int i = threadIdx.x; i < 4096; i += 256) {
        int h = i >> 6, c = i & 63;
        x2t[(size_t)h * NN + n0 + c] = tile[c][h];
    }
}

// ---------------- fused temporal: 4 pairs/wave, 4 channels/lane ----------------
// out written pair-contiguous: tflat[bn][w], bn = b*304+node, w = 0..20
__global__ __launch_bounds__(64) void k_temporal2(
    const float* __restrict__ data_x, const float* __restrict__ x2t,
    const float* __restrict__ w1, const float* __restrict__ b1,
    const float* __restrict__ w2, const float* __restrict__ b2,
    const float* __restrict__ w3, const float* __restrict__ b3,
    const float* __restrict__ v1, const float* __restrict__ vb1,
    const float* __restrict__ v2, const float* __restrict__ vb2,
    const float* __restrict__ v3, const float* __restrict__ vb3,
    const float* __restrict__ bn2g, const float* __restrict__ bn2b,
    float* __restrict__ tflat) {
    int bn0 = blockIdx.x * 4;
    int b = bn0 / NODES, node0 = bn0 % NODES;  // 304%4==0: block never straddles b
    int lane = threadIdx.x;
    int p = lane >> 4;           // pair within block (0..3)
    int c0 = (lane & 15) << 2;   // channel base (4 channels/lane)
    int node = node0 + p;

    __shared__ float xs[4][22];  // xs[p][j] = x[b, j-1, node_p], zero-padded ends
    for (int i = lane; i < 80; i += 64) {
        int pp = i / 20, t = i % 20;
        xs[pp][t + 1] = data_x[b * (TSTEPS * NODES) + t * NODES + node0 + pp];
    }
    if (lane < 4) { xs[lane][0] = 0.f; xs[lane][21] = 0.f; }

    // stage-1 weights (64,1,1,3): [c*3+k]; stage-2 (1,64,1,3): [c*3+k]
    float A1[4][3], A2[4][3], A3[4][3], B1v[4], B2v[4], B3v[4];
    float U1[4][3], U2[4][3], U3[4][3];
#pragma unroll
    for (int i = 0; i < 4; i++) {
        int c = c0 + i;
#pragma unroll
        for (int k = 0; k < 3; k++) {
            A1[i][k] = w1[c * 3 + k];
            A2[i][k] = w2[c * 3 + k];
            A3[i][k] = w3[c * 3 + k];
            U1[i][k] = v1[c * 3 + k];
            U2[i][k] = v2[c * 3 + k];
            U3[i][k] = v3[c * 3 + k];
        }
        B1v[i] = b1[c];
        B2v[i] = b2[c];
        B3v[i] = b3[c];
    }
    float cb1 = vb1[0], cb2 = vb2[0], cb3 = vb3[0];
    float s2 = bn2g[node] * rsqrtf(1.f + BN_EPS);
    float bb2 = bn2b[node];
    float* dst = tflat + (size_t)(bn0 + p) * 21;

    __syncthreads();

    // rotating h window: hA = h[:,j-2], hB = h[:,j-1], hC = h[:,j]
    float hA[4] = {0.f, 0.f, 0.f, 0.f}, hB[4] = {0.f, 0.f, 0.f, 0.f}, hC[4];

#pragma unroll
    for (int j = 0; j <= 21; j++) {
        if (j < 20) {
            float x0 = xs[p][j], x1 = xs[p][j + 1], x2v = xs[p][j + 2];
#pragma unroll
            for (int i = 0; i < 4; i++) {
                float pv = fmaf(A1[i][2], x2v, fmaf(A1[i][1], x1, fmaf(A1[i][0], x0, B1v[i])));
                float qv = fmaf(A2[i][2], x2v, fmaf(A2[i][1], x1, fmaf(A2[i][0], x0, B2v[i])));
                float rv = fmaf(A3[i][2], x2v, fmaf(A3[i][1], x1, fmaf(A3[i][0], x0, B3v[i])));
                float sg = 1.f / (1.f + __expf(-qv));
                hC[i] = fmaxf(fmaf(pv, sg, rv), 0.f);
            }
        } else if (j == 20) {
            // gfeat: x2t[b>>1][(b&1)*19456 + node*64 + c] — coalesced float4
            const float4 gv = *(const float4*)(x2t + (size_t)(b >> 1) * NN +
                                               (b & 1) * (NODES * HID) + node * HID + c0);
            hC[0] = fmaxf(gv.x, 0.f);
            hC[1] = fmaxf(gv.y, 0.f);
            hC[2] = fmaxf(gv.z, 0.f);
            hC[3] = fmaxf(gv.w, 0.f);
        } else {
#pragma unroll
            for (int i = 0; i < 4; i++) hC[i] = 0.f;
        }
        if (j >= 1) {
            int w = j - 1;
            float pp_ = 0.f, qq_ = 0.f, rr_ = 0.f;
#pragma unroll
            for (int i = 0; i < 4; i++) {
                pp_ = fmaf(U1[i][0], hA[i], pp_);
                pp_ = fmaf(U1[i][1], hB[i], pp_);
                pp_ = fmaf(U1[i][2], hC[i], pp_);
                qq_ = fmaf(U2[i][0], hA[i], qq_);
                qq_ = fmaf(U2[i][1], hB[i], qq_);
                qq_ = fmaf(U2[i][2], hC[i], qq_);
                rr_ = fmaf(U3[i][0], hA[i], rr_);
                rr_ = fmaf(U3[i][1], hB[i], rr_);
                rr_ = fmaf(U3[i][2], hC[i], rr_);
            }
            pp_ = rsum16(pp_);
            qq_ = rsum16(qq_);
            rr_ = rsum16(rr_);
            float P = pp_ + cb1, Q = qq_ + cb2, R = rr_ + cb3;
            float sg = 1.f / (1.f + __expf(-Q));
            float hv = fmaxf(fmaf(P, sg, R), 0.f);
            if ((lane & 15) == 0) dst[w] = fmaf(hv, s2, bb2);
        }
#pragma unroll
        for (int i = 0; i < 4; i++) {
            hA[i] = hB[i];
            hB[i] = hC[i];
        }
    }
}

// ---------------- bf16 converts ----------------
// tflat[bn][t2] -> Ab[b][t2*304+node] (bf16, K-padded)
__global__ __launch_bounds__(256) void k_cvtA(const float* __restrict__ tflat,
                                              short* __restrict__ dst) {
    int b = blockIdx.x;
    for (int kp = threadIdx.x; kp < KP1; kp += 256) {
        short v = 0;
        if (kp < FC1_IN) {
            int t2 = kp / NODES, node = kp % NODES;
            v = f2bf(tflat[((size_t)b * NODES + node) * 21 + t2]);
        }
        dst[(size_t)b * KP1 + kp] = v;
    }
}

// fcW [6384][2048] f32 -> Wt [2048][6400] bf16 (transposed, K-padded)
__global__ __launch_bounds__(256) void k_cvtW(const float* __restrict__ W,
                                              short* __restrict__ Wt) {
    __shared__ float t[32][33];
    int tx = threadIdx.x & 31, ty = threadIdx.x >> 5;  // 32 x 8
    int n0 = blockIdx.x * 32, k0 = blockIdx.y * 32;
#pragma unroll
    for (int r = 0; r < 32; r += 8) {
        int k = k0 + r + ty;
        t[r + ty][tx] = (k < FC1_IN) ? W[(size_t)k * FC1_OUT + n0 + tx] : 0.f;
    }
    __syncthreads();
#pragma unroll
    for (int r = 0; r < 32; r += 8) {
        int n = n0 + r + ty;
        Wt[(size_t)n * KP1 + k0 + tx] = f2bf(t[tx][r + ty]);
    }
}

// fc4W [2048][300] f32 -> W4t [304][2048] bf16 (transposed, N-padded)
__global__ __launch_bounds__(256) void k_cvtW4(const float* __restrict__ W,
                                               short* __restrict__ Wt) {
    __shared__ float t[32][33];
    int tx = threadIdx.x & 31, ty = threadIdx.x >> 5;
    int n0 = blockIdx.x * 32, k0 = blockIdx.y * 32;
#pragma unroll
    for (int r = 0; r < 32; r += 8) {
        int k = k0 + r + ty, n = n0 + tx;
        t[r + ty][tx] = (n < FC2_OUT) ? W[(size_t)k * FC2_OUT + n] : 0.f;
    }
    __syncthreads();
#pragma unroll
    for (int r = 0; r < 32; r += 8) {
        int n = n0 + r + ty;
        if (n < NP2) Wt[(size_t)n * FC1_OUT + k0 + tx] = f2bf(t[tx][r + ty]);
    }
}

// ---------------- FC1 MFMA GEMM: [128 x 6400] @ [6400 x 2048], split-K ----------------
#define KSPL1 8
#define KCH1  (KP1 / KSPL1)  // 800
__global__ __launch_bounds__(256) void k_gemm1(const short* __restrict__ Ab,
                                               const short* __restrict__ Wt,
                                               float* __restrict__ part) {
    int lane = threadIdx.x & 63, wv = threadIdx.x >> 6;
    int r = lane & 15, kg = lane >> 4;
    int nb = blockIdx.x * 64, sp = blockIdx.y;

    f32x4 acc[2][4] = {};
    const short* a0 = Ab + (size_t)(wv * 32 + r) * KP1;
    const short* a1 = a0 + (size_t)16 * KP1;
    const short* bp0 = Wt + (size_t)(nb + r) * KP1;
    const short* bp1 = bp0 + (size_t)16 * KP1;
    const short* bp2 = bp0 + (size_t)32 * KP1;
    const short* bp3 = bp0 + (size_t)48 * KP1;

    int k0 = sp * KCH1 + kg * 8;
#pragma unroll 1
    for (int s = 0; s < KCH1 / 32; s++, k0 += 32) {
        short8 av0 = *(const short8*)(a0 + k0);
        short8 av1 = *(const short8*)(a1 + k0);
        short8 bv0 = *(const short8*)(bp0 + k0);
        short8 bv1 = *(const short8*)(bp1 + k0);
        short8 bv2 = *(const short8*)(bp2 + k0);
        short8 bv3 = *(const short8*)(bp3 + k0);
        acc[0][0] = __builtin_amdgcn_mfma_f32_16x16x32_bf16(av0, bv0, acc[0][0], 0, 0, 0);
        acc[1][0] = __builtin_amdgcn_mfma_f32_16x16x32_bf16(av1, bv0, acc[1][0], 0, 0, 0);
        acc[0][1] = __builtin_amdgcn_mfma_f32_16x16x32_bf16(av0, bv1, acc[0][1], 0, 0, 0);
        acc[1][1] = __builtin_amdgcn_mfma_f32_16x16x32_bf16(av1, bv1, acc[1][1], 0, 0, 0);
        acc[0][2] = __builtin_amdgcn_mfma_f32_16x16x32_bf16(av0, bv2, acc[0][2], 0, 0, 0);
        acc[1][2] = __builtin_amdgcn_mfma_f32_16x16x32_bf16(av1, bv2, acc[1][2], 0, 0, 0);
        acc[0][3] = __builtin_amdgcn_mfma_f32_16x16x32_bf16(av0, bv3, acc[0][3], 0, 0, 0);
        acc[1][3] = __builtin_amdgcn_mfma_f32_16x16x32_bf16(av1, bv3, acc[1][3], 0, 0, 0);
    }

    float* dst = part + (size_t)sp * BATCH * FC1_OUT;
#pragma unroll
    for (int m = 0; m < 2; m++)
#pragma unroll
        for (int f = 0; f < 4; f++)
#pragma unroll
            for (int j = 0; j < 4; j++) {
                int row = wv * 32 + m * 16 + kg * 4 + j;
                int col = nb + f * 16 + r;
                dst[(size_t)row * FC1_OUT + col] = acc[m][f][j];
            }
}

// reduce split-K + bias + ReLU -> bf16 activations for FC2
__global__ __launch_bounds__(256) void k_reduce1(const float* __restrict__ part,
                                                 const float* __restrict__ bias,
                                                 short* __restrict__ Ab2) {
    int idx = blockIdx.x * 256 + threadIdx.x;  // b*2048+o
    int o = idx & (FC1_OUT - 1);
    float s = bias[o];
#pragma unroll
    for (int sp = 0; sp < KSPL1; sp++) s += part[(size_t)sp * BATCH * FC1_OUT + idx];
    Ab2[idx] = f2bf(fmaxf(s, 0.f));
}

// ---------------- FC2 MFMA GEMM: [128 x 2048] @ [2048 x 304], split-K ----------------
#define KSPL2 8
#define KCH2  (FC1_OUT / KSPL2)  // 256
__global__ __launch_bounds__(256) void k_gemm2(const short* __restrict__ Ab,
                                               const short* __restrict__ Wt,
                                               float* __restrict__ part) {
    int lane = threadIdx.x & 63, wv = threadIdx.x >> 6;
    int r = lane & 15, kg = lane >> 4;
    int nb = blockIdx.x * 16, sp = blockIdx.y;

    f32x4 acc[2] = {};
    const short* a0 = Ab + (size_t)(wv * 32 + r) * FC1_OUT;
    const short* a1 = a0 + (size_t)16 * FC1_OUT;
    const short* bp = Wt + (size_t)(nb + r) * FC1_OUT;

    int k0 = sp * KCH2 + kg * 8;
#pragma unroll
    for (int s = 0; s < KCH2 / 32; s++, k0 += 32) {
        short8 av0 = *(const short8*)(a0 + k0);
        short8 av1 = *(const short8*)(a1 + k0);
        short8 bv = *(const short8*)(bp + k0);
        acc[0] = __builtin_amdgcn_mfma_f32_16x16x32_bf16(av0, bv, acc[0], 0, 0, 0);
        acc[1] = __builtin_amdgcn_mfma_f32_16x16x32_bf16(av1, bv, acc[1], 0, 0, 0);
    }

    float* dst = part + (size_t)sp * BATCH * NP2;
#pragma unroll
    for (int m = 0; m < 2; m++)
#pragma unroll
        for (int j = 0; j < 4; j++) {
            int row = wv * 32 + m * 16 + kg * 4 + j;
            int col = nb + r;
            dst[(size_t)row * NP2 + col] = acc[m][j];
        }
}

__global__ __launch_bounds__(256) void k_reduce2(const float* __restrict__ part,
                                                 const float* __restrict__ bias,
                                                 float* __restrict__ out) {
    int idx = blockIdx.x * 256 + threadIdx.x;  // over BATCH*NP2
    if (idx >= BATCH * NP2) return;
    int b = idx / NP2, o = idx % NP2;
    float s = 0.f;
#pragma unroll
    for (int sp = 0; sp < KSPL2; sp++) s += part[(size_t)sp * BATCH * NP2 + idx];
    if (o < FC2_OUT) out[(size_t)b * FC2_OUT + o] = s + bias[o];
}

extern "C" void kernel_launch(void* const* d_in, const int* in_sizes, int n_in,
                              void* d_out, int out_size, void* d_ws, size_t ws_size,
                              hipStream_t stream) {
    const float* data_x = (const float*)d_in[0];
    const int* ei = (const int*)d_in[1];
    const float* ew = (const float*)d_in[2];
    const float* tc1w1 = (const float*)d_in[3];
    const float* tc1b1 = (const float*)d_in[4];
    const float* tc1w2 = (const float*)d_in[5];
    const float* tc1b2 = (const float*)d_in[6];
    const float* tc1w3 = (const float*)d_in[7];
    const float* tc1b3 = (const float*)d_in[8];
    const float* W0 = (const float*)d_in[9];
    const float* gb0 = (const float*)d_in[10];
    const float* bn0g = (const float*)d_in[11];
    const float* bn0b = (const float*)d_in[12];
    const float* W1 = (const float*)d_in[13];
    const float* gb1 = (const float*)d_in[14];
    const float* bn1g = (const float*)d_in[15];
    const float* bn1b = (const float*)d_in[16];
    const float* tc2w1 = (const float*)d_in[17];
    const float* tc2b1 = (const float*)d_in[18];
    const float* tc2w2 = (const float*)d_in[19];
    const float* tc2b2 = (const float*)d_in[20];
    const float* tc2w3 = (const float*)d_in[21];
    const float* tc2b3 = (const float*)d_in[22];
    const float* bn2g = (const float*)d_in[23];
    const float* bn2b = (const float*)d_in[24];
    const float* fcW = (const float*)d_in[25];
    const float* fcb = (const float*)d_in[26];
    const float* fc4W = (const float*)d_in[27];
    const float* fc4b = (const float*)d_in[28];
    float* out = (float*)d_out;

    char* ws = (char*)d_ws;
    // persistent region
    float* x2 = (float*)(ws + 0);                  // 9,961,472 B
    float* tflat = (float*)(ws + 9961472);         // 3,268,608 B  ([bn][21] layout)
    const size_t ARENA = 9961472 + 3268608;        // 13,230,080

    // arena A (CSR/GCN phase)
    size_t off = ARENA;
    auto alloc = [&](size_t bytes) -> void* {
        void* p = ws + off;
        off = (off + bytes + 255) & ~(size_t)255;
        return p;
    };
    int* cnt = (int*)alloc((size_t)NN * 4);
    int* rowptr = (int*)alloc((size_t)(NN + 1) * 4);
    int* cursor = (int*)alloc((size_t)NN * 4);
    int* row_s = (int*)alloc((size_t)NE * 4);
    float* w_s = (float*)alloc((size_t)NE * 4);
    float* dinv = (float*)alloc((size_t)NN * 4);
    float* h = (float*)alloc((size_t)NN * HID * 4);
    float* x1 = (float*)alloc((size_t)NN * HID * 4);

    // x2t overlaps arena A (written by k_xpose AFTER all CSR/GCN consumers done)
    float* x2t = (float*)(ws + ARENA);             // 9,961,472 B

    // arena C (FC phase) — overlaps arena A and x2t, used only after temporal
    off = ARENA;
    short* Ab = (short*)alloc((size_t)BATCH * KP1 * 2);
    short* Wt = (short*)alloc((size_t)FC1_OUT * KP1 * 2);
    float* part1 = (float*)alloc((size_t)KSPL1 * BATCH * FC1_OUT * 4);
    short* Ab2 = (short*)alloc((size_t)BATCH * FC1_OUT * 2);
    short* W4t = (short*)alloc((size_t)NP2 * FC1_OUT * 2);
    float* part2 = (float*)alloc((size_t)KSPL2 * BATCH * NP2 * 4);
    (void)ws_size; (void)in_sizes; (void)n_in; (void)out_size;

    // ---- CSR ----
    hipMemsetAsync(cnt, 0, (size_t)NN * 4, stream);
    k_count<<<(NE + 255) / 256, 256, 0, stream>>>(ei, cnt);
    k_scan<<<1, 1024, 0, stream>>>(cnt, rowptr, cursor);
    k_fill<<<(NE + 255) / 256, 256, 0, stream>>>(ei, ew, cursor, row_s, w_s);
    k_dinv<<<(NN + 255) / 256, 256, 0, stream>>>(rowptr, w_s, dinv);
    k_norm<<<(NN + 255) / 256, 256, 0, stream>>>(rowptr, row_s, dinv, w_s);

    // ---- GCN ----
    k_mmrow<GCNIN><<<NN, 64, 0, stream>>>(data_x, W0, h);
    k_gather<<<NN, 64, 0, stream>>>(rowptr, row_s, w_s, dinv, h, gb0, bn0g, bn0b, x1);
    k_mmrow<HID><<<NN, 64, 0, stream>>>(x1, W1, h);
    k_gather<<<NN, 64, 0, stream>>>(rowptr, row_s, w_s, dinv, h, gb1, bn1g, bn1b, x2);

    // ---- transpose x2 for coalesced gfeat ----
    k_xpose<<<NN / 64, 256, 0, stream>>>(x2, x2t);

    // ---- temporal (fused conv1 + concat + conv2 + BN2d) ----
    k_temporal2<<<NN / 4, 64, 0, stream>>>(data_x, x2t, tc1w1, tc1b1, tc1w2, tc1b2,
                                           tc1w3, tc1b3, tc2w1, tc2b1, tc2w2, tc2b2,
                                           tc2w3, tc2b3, bn2g, bn2b, tflat);

    // ---- FC (bf16 MFMA) ----
    k_cvtA<<<BATCH, 256, 0, stream>>>(tflat, Ab);
    {
        dim3 g(FC1_OUT / 32, KP1 / 32);
        k_cvtW<<<g, 256, 0, stream>>>(fcW, Wt);
    }
    {
        dim3 g(FC1_OUT / 64, KSPL1);
        k_gemm1<<<g, 256, 0, stream>>>(Ab, Wt, part1);
    }
    k_reduce1<<<BATCH * FC1_OUT / 256, 256, 0, stream>>>(part1, fcb, Ab2);
    {
        dim3 g((NP2 + 31) / 32, FC1_OUT / 32);
        k_cvtW4<<<g, 256, 0, stream>>>(fc4W, W4t);
    }
    {
        dim3 g(NP2 / 16, KSPL2);
        k_gemm2<<<g, 256, 0, stream>>>(Ab2, W4t, part2);
    }
    k_reduce2<<<(BATCH * NP2 + 255) / 256, 256, 0, stream>>>(part2, fc4b, out);
}